// Round 2
// baseline (1035.344 us; speedup 1.0000x reference)
//
#include <hip/hip_runtime.h>
#include <hip/hip_bf16.h>
#include <cmath>

#define B_ 4096
#define D_ 768
#define E_ 16
#define H_ 768
#define C_ 1000
#define CP_ 1024
#define K_ 768

typedef __bf16 bf16_t;
typedef __bf16 bf16x8 __attribute__((ext_vector_type(8)));
typedef float f32x4 __attribute__((ext_vector_type(4)));

__device__ __forceinline__ void async_lds16(const void* g, void* l) {
  __builtin_amdgcn_global_load_lds(
      (const __attribute__((address_space(1))) void*)g,
      (__attribute__((address_space(3))) void*)l, 16, 0, 0);
}

// ---------------- router + LayerNorm fused (both read feat once) ----------------
__global__ __launch_bounds__(256) void k_router_ln(
    const float* __restrict__ feat, const float* __restrict__ rw,
    const float* __restrict__ rb, float* __restrict__ gate_out,
    int* __restrict__ tk_idx, float* __restrict__ tk_val,
    bf16_t* __restrict__ xn) {
  int w = threadIdx.x >> 6, lane = threadIdx.x & 63;
  int b = blockIdx.x * 4 + w;
  float acc[E_];
#pragma unroll
  for (int e = 0; e < E_; ++e) acc[e] = 0.f;
  const float* frow = feat + (size_t)b * D_;
  float v[D_ / 64];
  float s = 0.f, sq = 0.f;
#pragma unroll
  for (int it = 0; it < D_ / 64; ++it) {
    int d = it * 64 + lane;
    float f = frow[d];
    v[it] = f; s += f; sq += f * f;
    const float4* r4 = reinterpret_cast<const float4*>(rw + (size_t)d * E_);
    float4 q0 = r4[0], q1 = r4[1], q2 = r4[2], q3 = r4[3];
    acc[0]  += f * q0.x; acc[1]  += f * q0.y; acc[2]  += f * q0.z; acc[3]  += f * q0.w;
    acc[4]  += f * q1.x; acc[5]  += f * q1.y; acc[6]  += f * q1.z; acc[7]  += f * q1.w;
    acc[8]  += f * q2.x; acc[9]  += f * q2.y; acc[10] += f * q2.z; acc[11] += f * q2.w;
    acc[12] += f * q3.x; acc[13] += f * q3.y; acc[14] += f * q3.z; acc[15] += f * q3.w;
  }
#pragma unroll
  for (int off = 32; off; off >>= 1) { s += __shfl_xor(s, off); sq += __shfl_xor(sq, off); }
  float mu = s * (1.f / D_);
  float var = sq * (1.f / D_) - mu * mu;
  float rs = rsqrtf(var + 1e-5f);
  bf16_t* o = xn + (size_t)b * D_;
#pragma unroll
  for (int it = 0; it < D_ / 64; ++it)
    o[it * 64 + lane] = (bf16_t)((v[it] - mu) * rs);
#pragma unroll
  for (int e = 0; e < E_; ++e) {
#pragma unroll
    for (int off = 32; off; off >>= 1) acc[e] += __shfl_xor(acc[e], off);
    acc[e] += rb[e];
  }
  if (lane == 0) {
    float mx = acc[0];
#pragma unroll
    for (int e = 1; e < E_; ++e) mx = fmaxf(mx, acc[e]);
    float p[E_]; float ps = 0.f;
#pragma unroll
    for (int e = 0; e < E_; ++e) { p[e] = expf(acc[e] - mx); ps += p[e]; }
    float inv = 1.f / ps;
    float* go = gate_out + (size_t)b * E_;
#pragma unroll
    for (int e = 0; e < E_; ++e) { p[e] *= inv; go[e] = p[e]; }
    float lg[E_];
#pragma unroll
    for (int e = 0; e < E_; ++e) lg[e] = acc[e];
    int idx4[4]; float v4[4]; float vs = 0.f;
#pragma unroll
    for (int k = 0; k < 4; ++k) {
      int bi = 0; float bv = -1e30f;
#pragma unroll
      for (int e = 0; e < E_; ++e) { if (lg[e] > bv) { bv = lg[e]; bi = e; } }
      idx4[k] = bi; v4[k] = p[bi]; vs += p[bi]; lg[bi] = -1e30f;
    }
    float nv = 1.f / vs;
#pragma unroll
    for (int k = 0; k < 4; ++k) { tk_idx[b * 4 + k] = idx4[k]; tk_val[b * 4 + k] = v4[k] * nv; }
  }
}

// ---------------- bias1 init: bias1 = b1 ----------------
__global__ __launch_bounds__(256) void k_bias_init(const float* __restrict__ b1,
                                                   float* __restrict__ bias1) {
  int i = blockIdx.x * 256 + threadIdx.x;
  bias1[i] = b1[i];
}

// ---- transpose+convert w1 (fold ln_g) + accumulate bias contrib lnb@w1 ----
__global__ void k_tw1(const float* __restrict__ w1, const float* __restrict__ lng,
                      const float* __restrict__ lnb, bf16_t* __restrict__ w1T,
                      float* __restrict__ bias1) {
  __shared__ float t[32][33];
  __shared__ float br[8][33];
  int e = blockIdx.z, dT = blockIdx.y * 32, hT = blockIdx.x * 32;
  int tx = threadIdx.x, ty = threadIdx.y;
  const float* w1e = w1 + (size_t)e * D_ * H_;
  const float* ge = lng + (size_t)e * D_;
  const float* lb = lnb + (size_t)e * D_;
  float bsum = 0.f;
#pragma unroll
  for (int r = 0; r < 4; ++r) {
    int d = dT + ty + r * 8;
    float val = w1e[(size_t)d * H_ + hT + tx];
    t[ty + r * 8][tx] = val * ge[d];
    bsum += lb[d] * val;
  }
  br[ty][tx] = bsum;
  __syncthreads();
  bf16_t* o = w1T + (size_t)e * H_ * D_;
#pragma unroll
  for (int r = 0; r < 4; ++r) {
    int h = hT + ty + r * 8;
    o[(size_t)h * D_ + dT + tx] = (bf16_t)t[tx][ty + r * 8];
  }
  if (ty == 0) {
    float a = 0.f;
#pragma unroll
    for (int z = 0; z < 8; ++z) a += br[z][tx];
    atomicAdd(&bias1[(size_t)e * H_ + hT + tx], a);
  }
}

// ---------------- transpose+convert w2 (pad C->1024 with zeros): w2T[e][c][h] ----------------
__global__ void k_tw2(const float* __restrict__ w2, bf16_t* __restrict__ w2T) {
  __shared__ float t[32][33];
  int e = blockIdx.z, hT = blockIdx.y * 32, cT = blockIdx.x * 32;
  int tx = threadIdx.x, ty = threadIdx.y;
  const float* w2e = w2 + (size_t)e * H_ * C_;
#pragma unroll
  for (int r = 0; r < 4; ++r) {
    int h = hT + ty + r * 8, c = cT + tx;
    t[ty + r * 8][tx] = (c < C_) ? w2e[(size_t)h * C_ + c] : 0.f;
  }
  __syncthreads();
  bf16_t* o = w2T + (size_t)e * CP_ * H_;
#pragma unroll
  for (int r = 0; r < 4; ++r) {
    int c = cT + ty + r * 8;
    o[(size_t)c * H_ + hT + tx] = (bf16_t)t[tx][ty + r * 8];
  }
}

// ---------------- 256x256 8-phase bf16 MFMA GEMM (GEMM1: xn @ w1T -> GELU -> Hact) ----------------
template <int MODE>
__global__ __launch_bounds__(512, 2) void k_gemm256(
    const bf16_t* __restrict__ Abase, size_t aStride,
    const bf16_t* __restrict__ Bt, int Np,
    const float* __restrict__ bias,
    bf16_t* __restrict__ outb, float* __restrict__ outf) {
  __shared__ __attribute__((aligned(16))) bf16_t smbuf[2][2][256 * 64];
  int id = blockIdx.x;
  int xcd = id & 7, seq = id >> 3;
  int e, m0, n0;
  if (MODE == 0) {
    int m = seq / 6, rr = seq % 6;
    e = xcd * 2 + rr / 3;
    m0 = m * 256;
    n0 = (rr % 3) * 256;
  } else {
    e = xcd * 2 + (seq >> 6);
    int rr = seq & 63;
    m0 = (rr >> 2) * 256;
    n0 = (rr & 3) * 256;
  }
  const bf16_t* A = Abase + (size_t)e * aStride + (size_t)m0 * K_;
  const bf16_t* Bp = Bt + ((size_t)e * Np + n0) * K_;

  int tid = threadIdx.x;
  int lane = tid & 63;
  int wid = tid >> 6;
  int wm = wid >> 2, wn = wid & 3;
  int fr = lane & 15, hi = lane >> 4;
  int sw0 = (hi ^ (fr & 7)) * 8;

  int srow = tid >> 3;
  int scg = (tid & 7) ^ (srow & 7);
  const bf16_t* asrc = A + (size_t)srow * K_ + scg * 8;
  const bf16_t* bsrc = Bp + (size_t)srow * K_ + scg * 8;

  f32x4 acc[8][4];
#pragma unroll
  for (int i = 0; i < 8; ++i)
#pragma unroll
    for (int j = 0; j < 4; ++j) acc[i][j] = f32x4{0.f, 0.f, 0.f, 0.f};

  auto STAGE = [&](int kt, int nb) {
    bf16_t* ad = &smbuf[nb][0][tid * 8];
    bf16_t* bd = &smbuf[nb][1][tid * 8];
    const bf16_t* as = asrc + kt * 64;
    const bf16_t* bs = bsrc + kt * 64;
#pragma unroll
    for (int s = 0; s < 4; ++s) {
      async_lds16(as + (size_t)s * 64 * K_, ad + s * 4096);
      async_lds16(bs + (size_t)s * 64 * K_, bd + s * 4096);
    }
  };

  bf16x8 af[4][2], bfr[2][2];
  auto COMPUTE = [&](int cur) {
    const bf16_t* Ala = &smbuf[cur][0][(wm * 128 + fr) * 64];
    const bf16_t* Bla = &smbuf[cur][1][(wn * 64 + fr) * 64];
#pragma unroll
    for (int q = 0; q < 4; ++q) {
      const int mq = q >> 1;
      const int nq = (q == 1 || q == 2);
      if (q == 0 || q == 2) {
#pragma unroll
        for (int i = 0; i < 4; ++i)
#pragma unroll
          for (int ks = 0; ks < 2; ++ks)
            af[i][ks] = *(const bf16x8*)&Ala[(mq * 64 + i * 16) * 64 + (sw0 ^ (ks * 32))];
      }
      if (q != 2) {
#pragma unroll
        for (int j = 0; j < 2; ++j)
#pragma unroll
          for (int ks = 0; ks < 2; ++ks)
            bfr[j][ks] = *(const bf16x8*)&Bla[(nq * 32 + j * 16) * 64 + (sw0 ^ (ks * 32))];
      }
      __builtin_amdgcn_s_barrier();
      __builtin_amdgcn_s_setprio(1);
#pragma unroll
      for (int i = 0; i < 4; ++i)
#pragma unroll
        for (int j = 0; j < 2; ++j)
#pragma unroll
          for (int ks = 0; ks < 2; ++ks)
            acc[mq * 4 + i][nq * 2 + j] = __builtin_amdgcn_mfma_f32_16x16x32_bf16(
                af[i][ks], bfr[j][ks], acc[mq * 4 + i][nq * 2 + j], 0, 0, 0);
      __builtin_amdgcn_s_setprio(0);
      __builtin_amdgcn_s_barrier();
    }
  };

  constexpr int NKT = K_ / 64;  // 12
  STAGE(0, 0);
  for (int t = 0; t < NKT - 1; ++t) {
    STAGE(t + 1, (t + 1) & 1);
    asm volatile("s_waitcnt vmcnt(8)" ::: "memory");
    __builtin_amdgcn_s_barrier();
    COMPUTE(t & 1);
  }
  asm volatile("s_waitcnt vmcnt(0)" ::: "memory");
  __builtin_amdgcn_s_barrier();
  COMPUTE((NKT - 1) & 1);

  int rb = hi * 4;
  int cl = fr;
#pragma unroll
  for (int i = 0; i < 8; ++i) {
#pragma unroll
    for (int j = 0; j < 4; ++j) {
      int n = n0 + wn * 64 + j * 16 + cl;
      if (MODE == 0) {
        float bs = bias[(size_t)e * H_ + n];
#pragma unroll
        for (int r = 0; r < 4; ++r) {
          int m = m0 + wm * 128 + i * 16 + rb + r;
          float vv = acc[i][j][r] + bs;
          vv = 0.5f * vv * (1.f + erff(vv * 0.70710678118654752f));
          outb[((size_t)e * B_ + m) * H_ + n] = (bf16_t)vv;
        }
      } else if (MODE == 1) {
        float bs = (n < C_) ? bias[(size_t)e * C_ + n] : 0.f;
#pragma unroll
        for (int r = 0; r < 4; ++r) {
          int m = m0 + wm * 128 + i * 16 + rb + r;
          outb[((size_t)e * B_ + m) * CP_ + n] = (bf16_t)(acc[i][j][r] + bs);
        }
      } else {
        if (n < C_) {
          float bs = bias[(size_t)e * C_ + n];
#pragma unroll
          for (int r = 0; r < 4; ++r) {
            int m = m0 + wm * 128 + i * 16 + rb + r;
            outf[((size_t)e * B_ + m) * C_ + n] = acc[i][j][r] + bs;
          }
        }
      }
    }
  }
}

// ---------------- fused GEMM2 + row softmax: Hact @ w2T + b2 -> softmax -> out1 ----------------
// Block: M=64 rows of one expert x N=1024 (full padded C). 512 thr = 8 waves, wave wn
// owns cols [wn*128, wn*128+128). BK=32, double-buffered. LDS granule(16B) layouts:
//   Bs: idx = kg*1024 + col  (kg = k/8 within tile), As: idx = kg*64 + row.
// Frag reads: 16 consecutive granules per quarter-wave -> conflict-free, no swizzle.
// Staging: 8 B-granules + 1 A-granule per thread (A duplicated across thread halves,
// identical-value write race is benign) -> uniform 9 loads/thread -> vmcnt(9) counted.
__global__ __launch_bounds__(512, 2) void k_gemm2_sm(
    const bf16_t* __restrict__ Hact, const bf16_t* __restrict__ w2T,
    const float* __restrict__ b2, float* __restrict__ out1) {
  __shared__ __attribute__((aligned(16))) bf16_t Bsm[2][32768];  // 2 x 64 KiB
  __shared__ __attribute__((aligned(16))) bf16_t Asm[2][2048];   // 2 x 4 KiB
  int id = blockIdx.x;
  int xcd = id & 7, seq = id >> 3;           // grid 1024 = 8 XCD x 128
  int e = xcd * 2 + (seq >> 6);              // all 64 m-blocks of an expert on one XCD
  int m0 = (seq & 63) * 64;
  const bf16_t* A = Hact + ((size_t)e * B_ + m0) * K_;
  const bf16_t* Bp = w2T + (size_t)e * CP_ * K_;

  int tid = threadIdx.x;
  int lane = tid & 63, wn = tid >> 6;
  int fr = lane & 15, hi = lane >> 4;

  f32x4 acc[4][8];
#pragma unroll
  for (int i = 0; i < 4; ++i)
#pragma unroll
    for (int j = 0; j < 8; ++j) acc[i][j] = f32x4{0.f, 0.f, 0.f, 0.f};

  // staging bases
  const bf16_t* bbase = Bp + (size_t)tid * K_;        // col = tid (s even part)
  int ga = tid & 255;
  int arow = ga & 63, akg = ga >> 6;
  const bf16_t* abase = A + (size_t)arow * K_ + akg * 8;

  auto STAGE = [&](int kt, int nb) {
    bf16_t* bd = &Bsm[nb][0];
#pragma unroll
    for (int s = 0; s < 8; ++s) {
      // granule g = s*512 + tid ; col = (s&1)*512 + tid ; kg = s>>1
      const bf16_t* src = bbase + (size_t)((s & 1) * 512) * K_ + (s >> 1) * 8 + kt * 32;
      async_lds16(src, bd + (s * 512 + tid) * 8);
    }
    async_lds16(abase + kt * 32, &Asm[nb][ga * 8]);
  };

  auto COMPUTE = [&](int cur) {
    bf16x8 af[4], bf[8];
#pragma unroll
    for (int i = 0; i < 4; ++i)
      af[i] = *(const bf16x8*)&Asm[cur][(hi * 64 + i * 16 + fr) * 8];
#pragma unroll
    for (int j = 0; j < 8; ++j)
      bf[j] = *(const bf16x8*)&Bsm[cur][(hi * 1024 + wn * 128 + j * 16 + fr) * 8];
    __builtin_amdgcn_s_setprio(1);
#pragma unroll
    for (int i = 0; i < 4; ++i)
#pragma unroll
      for (int j = 0; j < 8; ++j)
        acc[i][j] = __builtin_amdgcn_mfma_f32_16x16x32_bf16(af[i], bf[j], acc[i][j], 0, 0, 0);
    __builtin_amdgcn_s_setprio(0);
  };

  constexpr int NKT = K_ / 32;  // 24
  STAGE(0, 0);
  for (int t = 0; t < NKT - 1; ++t) {
    STAGE(t + 1, (t + 1) & 1);
    asm volatile("s_waitcnt vmcnt(9)" ::: "memory");
    __builtin_amdgcn_s_barrier();
    COMPUTE(t & 1);
    __builtin_amdgcn_s_barrier();
  }
  asm volatile("s_waitcnt vmcnt(0)" ::: "memory");
  __builtin_amdgcn_s_barrier();
  COMPUTE((NKT - 1) & 1);
  __syncthreads();

  // ---- epilogue: bias, masked row softmax over C=1000, write fp32 probs ----
  int colb[8]; bool val[8]; float bc[8];
#pragma unroll
  for (int j = 0; j < 8; ++j) {
    int col = wn * 128 + j * 16 + fr;
    colb[j] = col;
    val[j] = (col < C_);
    bc[j] = val[j] ? b2[(size_t)e * C_ + col] : 0.f;
  }
#pragma unroll
  for (int i = 0; i < 4; ++i)
#pragma unroll
    for (int j = 0; j < 8; ++j)
#pragma unroll
      for (int r = 0; r < 4; ++r) acc[i][j][r] += bc[j];

  float* red = (float*)&Asm[0][0];  // 2 KiB scratch (compute done)
  float rm[4][4];
  // per-row max: over this wave's cols, then across waves via LDS
#pragma unroll
  for (int i = 0; i < 4; ++i)
#pragma unroll
    for (int r = 0; r < 4; ++r) {
      float m = -1e30f;
#pragma unroll
      for (int j = 0; j < 8; ++j) m = val[j] ? fmaxf(m, acc[i][j][r]) : m;
#pragma unroll
      for (int off = 1; off < 16; off <<= 1) m = fmaxf(m, __shfl_xor(m, off));
      rm[i][r] = m;
    }
  if (fr == 0) {
#pragma unroll
    for (int i = 0; i < 4; ++i)
#pragma unroll
      for (int r = 0; r < 4; ++r) red[wn * 64 + i * 16 + hi * 4 + r] = rm[i][r];
  }
  __syncthreads();
#pragma unroll
  for (int i = 0; i < 4; ++i)
#pragma unroll
    for (int r = 0; r < 4; ++r) {
      int row = i * 16 + hi * 4 + r;
      float m = red[row];
#pragma unroll
      for (int w = 1; w < 8; ++w) m = fmaxf(m, red[w * 64 + row]);
      rm[i][r] = m;
    }
  __syncthreads();
  // exp + per-row sum
  float rs[4][4];
#pragma unroll
  for (int i = 0; i < 4; ++i)
#pragma unroll
    for (int r = 0; r < 4; ++r) {
      float s = 0.f;
#pragma unroll
      for (int j = 0; j < 8; ++j) {
        float p = val[j] ? __expf(acc[i][j][r] - rm[i][r]) : 0.f;
        acc[i][j][r] = p; s += p;
      }
#pragma unroll
      for (int off = 1; off < 16; off <<= 1) s += __shfl_xor(s, off);
      rs[i][r] = s;
    }
  if (fr == 0) {
#pragma unroll
    for (int i = 0; i < 4; ++i)
#pragma unroll
      for (int r = 0; r < 4; ++r) red[wn * 64 + i * 16 + hi * 4 + r] = rs[i][r];
  }
  __syncthreads();
#pragma unroll
  for (int i = 0; i < 4; ++i)
#pragma unroll
    for (int r = 0; r < 4; ++r) {
      int row = i * 16 + hi * 4 + r;
      float s = red[row];
#pragma unroll
      for (int w = 1; w < 8; ++w) s += red[w * 64 + row];
      float inv = 1.f / s;
      float* orow = out1 + ((size_t)e * B_ + m0 + row) * C_;
#pragma unroll
      for (int j = 0; j < 8; ++j)
        if (val[j]) orow[colb[j]] = acc[i][j][r] * inv;
    }
}

// ---------------- market_probs = sum_k tkv[b,k] * all_probs[tki[b,k]][b][:] ----------------
__global__ __launch_bounds__(256) void k_market(const float* __restrict__ allp,
                                                const int* __restrict__ tki,
                                                const float* __restrict__ tkv,
                                                float* __restrict__ out0) {
  int b = blockIdx.y;
  int c = blockIdx.x * 256 + threadIdx.x;
  if (c >= C_) return;
  const int* ix = tki + (size_t)b * 4;
  const float* vv = tkv + (size_t)b * 4;
  float s = 0.f;
#pragma unroll
  for (int k = 0; k < 4; ++k)
    s += vv[k] * allp[((size_t)ix[k] * B_ + b) * C_ + c];
  out0[(size_t)b * C_ + c] = s;
}

extern "C" void kernel_launch(void* const* d_in, const int* in_sizes, int n_in,
                              void* d_out, int out_size, void* d_ws, size_t ws_size,
                              hipStream_t stream) {
  const float* feat = (const float*)d_in[0];
  const float* rw   = (const float*)d_in[1];
  const float* rb   = (const float*)d_in[2];
  const float* lng  = (const float*)d_in[3];
  const float* lnb  = (const float*)d_in[4];
  const float* w1   = (const float*)d_in[5];
  const float* b1   = (const float*)d_in[6];
  const float* w2   = (const float*)d_in[7];
  const float* b2   = (const float*)d_in[8];

  float* out0 = (float*)d_out;                   // market_probs [4096,1000]
  float* out1 = out0 + (size_t)B_ * C_;          // all_probs [16,4096,1000]
  float* out2 = out1 + (size_t)E_ * B_ * C_;     // gate_probs [4096,16]

  char* ws = (char*)d_ws;
  size_t off = 0;
  auto take = [&](size_t bytes) -> void* {
    void* p = ws + off;
    off += (bytes + 255) & ~(size_t)255;
    return p;
  };
  bf16_t* xn   = (bf16_t*)take((size_t)B_ * D_ * 2);
  bf16_t* w1T  = (bf16_t*)take((size_t)E_ * H_ * D_ * 2);
  bf16_t* w2T  = (bf16_t*)take((size_t)E_ * CP_ * H_ * 2);
  float* bias1 = (float*)take((size_t)E_ * H_ * 4);
  int* tki     = (int*)take((size_t)B_ * 4 * 4);
  float* tkv   = (float*)take((size_t)B_ * 4 * 4);
  bf16_t* Hact = (bf16_t*)take((size_t)E_ * B_ * H_ * 2);

  k_router_ln<<<B_ / 4, 256, 0, stream>>>(feat, rw, rb, out2, tki, tkv, xn);
  k_bias_init<<<E_ * H_ / 256, 256, 0, stream>>>(b1, bias1);
  k_tw1<<<dim3(24, 24, E_), dim3(32, 8), 0, stream>>>(w1, lng, lnb, w1T, bias1);
  k_tw2<<<dim3(32, 24, E_), dim3(32, 8), 0, stream>>>(w2, w2T);
  // GEMM1: per expert M=4096, N=768 -> 48 tiles x 16 experts = 768 blocks
  k_gemm256<0><<<E_ * 16 * 3, 512, 0, stream>>>(xn, 0, w1T, H_, bias1, Hact, nullptr);
  // GEMM2 fused with softmax: 16 experts x 64 m-blocks = 1024 blocks
  k_gemm2_sm<<<E_ * 64, 512, 0, stream>>>(Hact, w2T, b2, out1);
  k_market<<<dim3(4, B_), 256, 0, stream>>>(out1, tki, tkv, out0);
}

// Round 3
// 771.441 us; speedup vs baseline: 1.3421x; 1.3421x over previous
//
#include <hip/hip_runtime.h>
#include <hip/hip_bf16.h>
#include <cmath>

#define B_ 4096
#define D_ 768
#define E_ 16
#define H_ 768
#define C_ 1000
#define CP_ 1024
#define K_ 768

typedef __bf16 bf16_t;
typedef __bf16 bf16x8 __attribute__((ext_vector_type(8)));
typedef float f32x4 __attribute__((ext_vector_type(4)));

__device__ __forceinline__ void async_lds16(const void* g, void* l) {
  __builtin_amdgcn_global_load_lds(
      (const __attribute__((address_space(1))) void*)g,
      (__attribute__((address_space(3))) void*)l, 16, 0, 0);
}

// ---------------- router + LayerNorm fused (both read feat once) ----------------
__global__ __launch_bounds__(256) void k_router_ln(
    const float* __restrict__ feat, const float* __restrict__ rw,
    const float* __restrict__ rb, float* __restrict__ gate_out,
    int* __restrict__ tk_idx, float* __restrict__ tk_val,
    bf16_t* __restrict__ xn) {
  int w = threadIdx.x >> 6, lane = threadIdx.x & 63;
  int b = blockIdx.x * 4 + w;
  float acc[E_];
#pragma unroll
  for (int e = 0; e < E_; ++e) acc[e] = 0.f;
  const float* frow = feat + (size_t)b * D_;
  float v[D_ / 64];
  float s = 0.f, sq = 0.f;
#pragma unroll
  for (int it = 0; it < D_ / 64; ++it) {
    int d = it * 64 + lane;
    float f = frow[d];
    v[it] = f; s += f; sq += f * f;
    const float4* r4 = reinterpret_cast<const float4*>(rw + (size_t)d * E_);
    float4 q0 = r4[0], q1 = r4[1], q2 = r4[2], q3 = r4[3];
    acc[0]  += f * q0.x; acc[1]  += f * q0.y; acc[2]  += f * q0.z; acc[3]  += f * q0.w;
    acc[4]  += f * q1.x; acc[5]  += f * q1.y; acc[6]  += f * q1.z; acc[7]  += f * q1.w;
    acc[8]  += f * q2.x; acc[9]  += f * q2.y; acc[10] += f * q2.z; acc[11] += f * q2.w;
    acc[12] += f * q3.x; acc[13] += f * q3.y; acc[14] += f * q3.z; acc[15] += f * q3.w;
  }
#pragma unroll
  for (int off = 32; off; off >>= 1) { s += __shfl_xor(s, off); sq += __shfl_xor(sq, off); }
  float mu = s * (1.f / D_);
  float var = sq * (1.f / D_) - mu * mu;
  float rs = rsqrtf(var + 1e-5f);
  bf16_t* o = xn + (size_t)b * D_;
#pragma unroll
  for (int it = 0; it < D_ / 64; ++it)
    o[it * 64 + lane] = (bf16_t)((v[it] - mu) * rs);
#pragma unroll
  for (int e = 0; e < E_; ++e) {
#pragma unroll
    for (int off = 32; off; off >>= 1) acc[e] += __shfl_xor(acc[e], off);
    acc[e] += rb[e];
  }
  if (lane == 0) {
    float mx = acc[0];
#pragma unroll
    for (int e = 1; e < E_; ++e) mx = fmaxf(mx, acc[e]);
    float p[E_]; float ps = 0.f;
#pragma unroll
    for (int e = 0; e < E_; ++e) { p[e] = expf(acc[e] - mx); ps += p[e]; }
    float inv = 1.f / ps;
    float* go = gate_out + (size_t)b * E_;
#pragma unroll
    for (int e = 0; e < E_; ++e) { p[e] *= inv; go[e] = p[e]; }
    float lg[E_];
#pragma unroll
    for (int e = 0; e < E_; ++e) lg[e] = acc[e];
    int idx4[4]; float v4[4]; float vs = 0.f;
#pragma unroll
    for (int k = 0; k < 4; ++k) {
      int bi = 0; float bv = -1e30f;
#pragma unroll
      for (int e = 0; e < E_; ++e) { if (lg[e] > bv) { bv = lg[e]; bi = e; } }
      idx4[k] = bi; v4[k] = p[bi]; vs += p[bi]; lg[bi] = -1e30f;
    }
    float nv = 1.f / vs;
#pragma unroll
    for (int k = 0; k < 4; ++k) { tk_idx[b * 4 + k] = idx4[k]; tk_val[b * 4 + k] = v4[k] * nv; }
  }
}

// ---------------- bias1 init: bias1 = b1 ----------------
__global__ __launch_bounds__(256) void k_bias_init(const float* __restrict__ b1,
                                                   float* __restrict__ bias1) {
  int i = blockIdx.x * 256 + threadIdx.x;
  bias1[i] = b1[i];
}

// ---- transpose+convert w1 (fold ln_g) + accumulate bias contrib lnb@w1 ----
__global__ void k_tw1(const float* __restrict__ w1, const float* __restrict__ lng,
                      const float* __restrict__ lnb, bf16_t* __restrict__ w1T,
                      float* __restrict__ bias1) {
  __shared__ float t[32][33];
  __shared__ float br[8][33];
  int e = blockIdx.z, dT = blockIdx.y * 32, hT = blockIdx.x * 32;
  int tx = threadIdx.x, ty = threadIdx.y;
  const float* w1e = w1 + (size_t)e * D_ * H_;
  const float* ge = lng + (size_t)e * D_;
  const float* lb = lnb + (size_t)e * D_;
  float bsum = 0.f;
#pragma unroll
  for (int r = 0; r < 4; ++r) {
    int d = dT + ty + r * 8;
    float val = w1e[(size_t)d * H_ + hT + tx];
    t[ty + r * 8][tx] = val * ge[d];
    bsum += lb[d] * val;
  }
  br[ty][tx] = bsum;
  __syncthreads();
  bf16_t* o = w1T + (size_t)e * H_ * D_;
#pragma unroll
  for (int r = 0; r < 4; ++r) {
    int h = hT + ty + r * 8;
    o[(size_t)h * D_ + dT + tx] = (bf16_t)t[tx][ty + r * 8];
  }
  if (ty == 0) {
    float a = 0.f;
#pragma unroll
    for (int z = 0; z < 8; ++z) a += br[z][tx];
    atomicAdd(&bias1[(size_t)e * H_ + hT + tx], a);
  }
}

// ---------------- transpose+convert w2 (pad C->1024 with zeros): w2T[e][c][h] ----------------
__global__ void k_tw2(const float* __restrict__ w2, bf16_t* __restrict__ w2T) {
  __shared__ float t[32][33];
  int e = blockIdx.z, hT = blockIdx.y * 32, cT = blockIdx.x * 32;
  int tx = threadIdx.x, ty = threadIdx.y;
  const float* w2e = w2 + (size_t)e * H_ * C_;
#pragma unroll
  for (int r = 0; r < 4; ++r) {
    int h = hT + ty + r * 8, c = cT + tx;
    t[ty + r * 8][tx] = (c < C_) ? w2e[(size_t)h * C_ + c] : 0.f;
  }
  __syncthreads();
  bf16_t* o = w2T + (size_t)e * CP_ * H_;
#pragma unroll
  for (int r = 0; r < 4; ++r) {
    int c = cT + ty + r * 8;
    o[(size_t)c * H_ + hT + tx] = (bf16_t)t[tx][ty + r * 8];
  }
}

// ---------------- 256x256 8-phase bf16 MFMA GEMM (GEMM1: xn @ w1T -> GELU -> Hact) ----------------
template <int MODE>
__global__ __launch_bounds__(512, 2) void k_gemm256(
    const bf16_t* __restrict__ Abase, size_t aStride,
    const bf16_t* __restrict__ Bt, int Np,
    const float* __restrict__ bias,
    bf16_t* __restrict__ outb, float* __restrict__ outf) {
  __shared__ __attribute__((aligned(16))) bf16_t smbuf[2][2][256 * 64];
  int id = blockIdx.x;
  int xcd = id & 7, seq = id >> 3;
  int e, m0, n0;
  if (MODE == 0) {
    int m = seq / 6, rr = seq % 6;
    e = xcd * 2 + rr / 3;
    m0 = m * 256;
    n0 = (rr % 3) * 256;
  } else {
    e = xcd * 2 + (seq >> 6);
    int rr = seq & 63;
    m0 = (rr >> 2) * 256;
    n0 = (rr & 3) * 256;
  }
  const bf16_t* A = Abase + (size_t)e * aStride + (size_t)m0 * K_;
  const bf16_t* Bp = Bt + ((size_t)e * Np + n0) * K_;

  int tid = threadIdx.x;
  int lane = tid & 63;
  int wid = tid >> 6;
  int wm = wid >> 2, wn = wid & 3;
  int fr = lane & 15, hi = lane >> 4;
  int sw0 = (hi ^ (fr & 7)) * 8;

  int srow = tid >> 3;
  int scg = (tid & 7) ^ (srow & 7);
  const bf16_t* asrc = A + (size_t)srow * K_ + scg * 8;
  const bf16_t* bsrc = Bp + (size_t)srow * K_ + scg * 8;

  f32x4 acc[8][4];
#pragma unroll
  for (int i = 0; i < 8; ++i)
#pragma unroll
    for (int j = 0; j < 4; ++j) acc[i][j] = f32x4{0.f, 0.f, 0.f, 0.f};

  auto STAGE = [&](int kt, int nb) {
    bf16_t* ad = &smbuf[nb][0][tid * 8];
    bf16_t* bd = &smbuf[nb][1][tid * 8];
    const bf16_t* as = asrc + kt * 64;
    const bf16_t* bs = bsrc + kt * 64;
#pragma unroll
    for (int s = 0; s < 4; ++s) {
      async_lds16(as + (size_t)s * 64 * K_, ad + s * 4096);
      async_lds16(bs + (size_t)s * 64 * K_, bd + s * 4096);
    }
  };

  bf16x8 af[4][2], bfr[2][2];
  auto COMPUTE = [&](int cur) {
    const bf16_t* Ala = &smbuf[cur][0][(wm * 128 + fr) * 64];
    const bf16_t* Bla = &smbuf[cur][1][(wn * 64 + fr) * 64];
#pragma unroll
    for (int q = 0; q < 4; ++q) {
      const int mq = q >> 1;
      const int nq = (q == 1 || q == 2);
      if (q == 0 || q == 2) {
#pragma unroll
        for (int i = 0; i < 4; ++i)
#pragma unroll
          for (int ks = 0; ks < 2; ++ks)
            af[i][ks] = *(const bf16x8*)&Ala[(mq * 64 + i * 16) * 64 + (sw0 ^ (ks * 32))];
      }
      if (q != 2) {
#pragma unroll
        for (int j = 0; j < 2; ++j)
#pragma unroll
          for (int ks = 0; ks < 2; ++ks)
            bfr[j][ks] = *(const bf16x8*)&Bla[(nq * 32 + j * 16) * 64 + (sw0 ^ (ks * 32))];
      }
      __builtin_amdgcn_s_barrier();
      __builtin_amdgcn_s_setprio(1);
#pragma unroll
      for (int i = 0; i < 4; ++i)
#pragma unroll
        for (int j = 0; j < 2; ++j)
#pragma unroll
          for (int ks = 0; ks < 2; ++ks)
            acc[mq * 4 + i][nq * 2 + j] = __builtin_amdgcn_mfma_f32_16x16x32_bf16(
                af[i][ks], bfr[j][ks], acc[mq * 4 + i][nq * 2 + j], 0, 0, 0);
      __builtin_amdgcn_s_setprio(0);
      __builtin_amdgcn_s_barrier();
    }
  };

  constexpr int NKT = K_ / 64;  // 12
  STAGE(0, 0);
  for (int t = 0; t < NKT - 1; ++t) {
    STAGE(t + 1, (t + 1) & 1);
    asm volatile("s_waitcnt vmcnt(8)" ::: "memory");
    __builtin_amdgcn_s_barrier();
    COMPUTE(t & 1);
  }
  asm volatile("s_waitcnt vmcnt(0)" ::: "memory");
  __builtin_amdgcn_s_barrier();
  COMPUTE((NKT - 1) & 1);

  int rb = hi * 4;
  int cl = fr;
#pragma unroll
  for (int i = 0; i < 8; ++i) {
#pragma unroll
    for (int j = 0; j < 4; ++j) {
      int n = n0 + wn * 64 + j * 16 + cl;
      if (MODE == 0) {
        float bs = bias[(size_t)e * H_ + n];
#pragma unroll
        for (int r = 0; r < 4; ++r) {
          int m = m0 + wm * 128 + i * 16 + rb + r;
          float vv = acc[i][j][r] + bs;
          vv = 0.5f * vv * (1.f + erff(vv * 0.70710678118654752f));
          outb[((size_t)e * B_ + m) * H_ + n] = (bf16_t)vv;
        }
      } else if (MODE == 1) {
        float bs = (n < C_) ? bias[(size_t)e * C_ + n] : 0.f;
#pragma unroll
        for (int r = 0; r < 4; ++r) {
          int m = m0 + wm * 128 + i * 16 + rb + r;
          outb[((size_t)e * B_ + m) * CP_ + n] = (bf16_t)(acc[i][j][r] + bs);
        }
      } else {
        if (n < C_) {
          float bs = bias[(size_t)e * C_ + n];
#pragma unroll
          for (int r = 0; r < 4; ++r) {
            int m = m0 + wm * 128 + i * 16 + rb + r;
            outf[((size_t)e * B_ + m) * C_ + n] = acc[i][j][r] + bs;
          }
        }
      }
    }
  }
}

// ---------------- fused GEMM2 + row softmax: Hact @ w2T + b2 -> softmax -> out1 ----------------
// Block: M=64 rows of one expert x N=1024 (full padded C). 512 thr = 8 waves, wave wn
// owns cols [wn*128, wn*128+128). BK=32, double-buffered.
// LDS layout (both A and B): [row][4 granules of 16B], physical granule within row
//   = kg ^ (row&3)  (involution; applied on stage SOURCE and on frag READ — linear
//   gload_lds dest). Staging: 4 consecutive lanes cover one row's 64 contiguous
//   bytes (kg-permuted within segment) -> fully coalesced 64-B segments.
// Uniform 9 loads/thread/K-tile (A duplicated across thread halves, benign
// identical-value race) -> counted vmcnt(9), never drained in the main loop.
__global__ __launch_bounds__(512, 2) void k_gemm2_sm(
    const bf16_t* __restrict__ Hact, const bf16_t* __restrict__ w2T,
    const float* __restrict__ b2, float* __restrict__ out1) {
  __shared__ __attribute__((aligned(16))) bf16_t Bsm[2][32768];  // 2 x 64 KiB
  __shared__ __attribute__((aligned(16))) bf16_t Asm[2][2048];   // 2 x 4 KiB
  int id = blockIdx.x;
  int xcd = id & 7, seq = id >> 3;           // grid 1024 = 8 XCD x 128
  int e = xcd * 2 + (seq >> 6);              // all 64 m-blocks of an expert on one XCD
  int m0 = (seq & 63) * 64;
  const bf16_t* A = Hact + ((size_t)e * B_ + m0) * K_;
  const bf16_t* Bp = w2T + (size_t)e * CP_ * K_;

  int tid = threadIdx.x;
  int lane = tid & 63, wn = tid >> 6;
  int fr = lane & 15, hi = lane >> 4;

  f32x4 acc[4][8];
#pragma unroll
  for (int i = 0; i < 4; ++i)
#pragma unroll
    for (int j = 0; j < 8; ++j) acc[i][j] = f32x4{0.f, 0.f, 0.f, 0.f};

  // B staging: physical granule p = s*512 + tid; row = p>>2 = s*128 + (tid>>2);
  // logical kg = (p&3) ^ (row&3) = (tid&3) ^ ((tid>>2)&3).
  int brow = tid >> 2;
  int bkg = (tid & 3) ^ (brow & 3);
  const bf16_t* bbase = Bp + (size_t)brow * K_ + bkg * 8;   // + s*128*K_ per s
  // A staging: p2 = tid&255; row = p2>>2; kg = (p2&3) ^ (row&3)  (same formula)
  int ga = tid & 255;
  const bf16_t* abase = A + (size_t)(ga >> 2) * K_ + (((ga & 3) ^ ((ga >> 2) & 3)) * 8);

  auto STAGE = [&](int kt, int nb) {
    bf16_t* bd = &Bsm[nb][tid * 8];
    const bf16_t* bs = bbase + kt * 32;
#pragma unroll
    for (int s = 0; s < 8; ++s)
      async_lds16(bs + (size_t)(s * 128) * K_, bd + s * 4096);
    async_lds16(abase + kt * 32, &Asm[nb][ga * 8]);
  };

  // frag read: logical (row, k-group hi) -> phys granule = row*4 + (hi ^ (row&3));
  // row&3 == fr&3 since row = 16*i + fr.
  int rsw = hi ^ (fr & 3);
  auto COMPUTE = [&](int cur) {
    bf16x8 af[4], bf[8];
#pragma unroll
    for (int i = 0; i < 4; ++i)
      af[i] = *(const bf16x8*)&Asm[cur][((i * 16 + fr) * 4 + rsw) * 8];
#pragma unroll
    for (int j = 0; j < 8; ++j)
      bf[j] = *(const bf16x8*)&Bsm[cur][((wn * 128 + j * 16 + fr) * 4 + rsw) * 8];
    __builtin_amdgcn_s_setprio(1);
#pragma unroll
    for (int i = 0; i < 4; ++i)
#pragma unroll
      for (int j = 0; j < 8; ++j)
        acc[i][j] = __builtin_amdgcn_mfma_f32_16x16x32_bf16(af[i], bf[j], acc[i][j], 0, 0, 0);
    __builtin_amdgcn_s_setprio(0);
  };

  constexpr int NKT = K_ / 32;  // 24
  STAGE(0, 0);
  for (int t = 0; t < NKT - 1; ++t) {
    STAGE(t + 1, (t + 1) & 1);
    asm volatile("s_waitcnt vmcnt(9)" ::: "memory");
    __builtin_amdgcn_s_barrier();
    COMPUTE(t & 1);
    __builtin_amdgcn_s_barrier();
  }
  asm volatile("s_waitcnt vmcnt(0)" ::: "memory");
  __builtin_amdgcn_s_barrier();
  COMPUTE((NKT - 1) & 1);
  __syncthreads();

  // ---- epilogue: bias, masked row softmax over C=1000, write fp32 probs ----
  int colb[8]; bool val[8]; float bc[8];
#pragma unroll
  for (int j = 0; j < 8; ++j) {
    int col = wn * 128 + j * 16 + fr;
    colb[j] = col;
    val[j] = (col < C_);
    bc[j] = val[j] ? b2[(size_t)e * C_ + col] : 0.f;
  }
#pragma unroll
  for (int i = 0; i < 4; ++i)
#pragma unroll
    for (int j = 0; j < 8; ++j)
#pragma unroll
      for (int r = 0; r < 4; ++r) acc[i][j][r] += bc[j];

  float* red = (float*)&Asm[0][0];  // 2 KiB scratch (compute done)
  float rm[4][4];
#pragma unroll
  for (int i = 0; i < 4; ++i)
#pragma unroll
    for (int r = 0; r < 4; ++r) {
      float m = -1e30f;
#pragma unroll
      for (int j = 0; j < 8; ++j) m = val[j] ? fmaxf(m, acc[i][j][r]) : m;
#pragma unroll
      for (int off = 1; off < 16; off <<= 1) m = fmaxf(m, __shfl_xor(m, off));
      rm[i][r] = m;
    }
  if (fr == 0) {
#pragma unroll
    for (int i = 0; i < 4; ++i)
#pragma unroll
      for (int r = 0; r < 4; ++r) red[wn * 64 + i * 16 + hi * 4 + r] = rm[i][r];
  }
  __syncthreads();
#pragma unroll
  for (int i = 0; i < 4; ++i)
#pragma unroll
    for (int r = 0; r < 4; ++r) {
      int row = i * 16 + hi * 4 + r;
      float m = red[row];
#pragma unroll
      for (int w = 1; w < 8; ++w) m = fmaxf(m, red[w * 64 + row]);
      rm[i][r] = m;
    }
  __syncthreads();
  float rs[4][4];
#pragma unroll
  for (int i = 0; i < 4; ++i)
#pragma unroll
    for (int r = 0; r < 4; ++r) {
      float s = 0.f;
#pragma unroll
      for (int j = 0; j < 8; ++j) {
        float p = val[j] ? __expf(acc[i][j][r] - rm[i][r]) : 0.f;
        acc[i][j][r] = p; s += p;
      }
#pragma unroll
      for (int off = 1; off < 16; off <<= 1) s += __shfl_xor(s, off);
      rs[i][r] = s;
    }
  if (fr == 0) {
#pragma unroll
    for (int i = 0; i < 4; ++i)
#pragma unroll
      for (int r = 0; r < 4; ++r) red[wn * 64 + i * 16 + hi * 4 + r] = rs[i][r];
  }
  __syncthreads();
#pragma unroll
  for (int i = 0; i < 4; ++i)
#pragma unroll
    for (int r = 0; r < 4; ++r) {
      int row = i * 16 + hi * 4 + r;
      float s = red[row];
#pragma unroll
      for (int w = 1; w < 8; ++w) s += red[w * 64 + row];
      float inv = 1.f / s;
      float* orow = out1 + ((size_t)e * B_ + m0 + row) * C_;
#pragma unroll
      for (int j = 0; j < 8; ++j)
        if (val[j]) orow[colb[j]] = acc[i][j][r] * inv;
    }
}

// ---------------- market_probs = sum_k tkv[b,k] * all_probs[tki[b,k]][b][:] ----------------
__global__ __launch_bounds__(256) void k_market(const float* __restrict__ allp,
                                                const int* __restrict__ tki,
                                                const float* __restrict__ tkv,
                                                float* __restrict__ out0) {
  int b = blockIdx.y;
  int c = blockIdx.x * 256 + threadIdx.x;
  if (c >= C_) return;
  const int* ix = tki + (size_t)b * 4;
  const float* vv = tkv + (size_t)b * 4;
  float s = 0.f;
#pragma unroll
  for (int k = 0; k < 4; ++k)
    s += vv[k] * allp[((size_t)ix[k] * B_ + b) * C_ + c];
  out0[(size_t)b * C_ + c] = s;
}

extern "C" void kernel_launch(void* const* d_in, const int* in_sizes, int n_in,
                              void* d_out, int out_size, void* d_ws, size_t ws_size,
                              hipStream_t stream) {
  const float* feat = (const float*)d_in[0];
  const float* rw   = (const float*)d_in[1];
  const float* rb   = (const float*)d_in[2];
  const float* lng  = (const float*)d_in[3];
  const float* lnb  = (const float*)d_in[4];
  const float* w1   = (const float*)d_in[5];
  const float* b1   = (const float*)d_in[6];
  const float* w2   = (const float*)d_in[7];
  const float* b2   = (const float*)d_in[8];

  float* out0 = (float*)d_out;                   // market_probs [4096,1000]
  float* out1 = out0 + (size_t)B_ * C_;          // all_probs [16,4096,1000]
  float* out2 = out1 + (size_t)E_ * B_ * C_;     // gate_probs [4096,16]

  char* ws = (char*)d_ws;
  size_t off = 0;
  auto take = [&](size_t bytes) -> void* {
    void* p = ws + off;
    off += (bytes + 255) & ~(size_t)255;
    return p;
  };
  bf16_t* xn   = (bf16_t*)take((size_t)B_ * D_ * 2);
  bf16_t* w1T  = (bf16_t*)take((size_t)E_ * H_ * D_ * 2);
  bf16_t* w2T  = (bf16_t*)take((size_t)E_ * CP_ * H_ * 2);
  float* bias1 = (float*)take((size_t)E_ * H_ * 4);
  int* tki     = (int*)take((size_t)B_ * 4 * 4);
  float* tkv   = (float*)take((size_t)B_ * 4 * 4);
  bf16_t* Hact = (bf16_t*)take((size_t)E_ * B_ * H_ * 2);

  k_router_ln<<<B_ / 4, 256, 0, stream>>>(feat, rw, rb, out2, tki, tkv, xn);
  k_bias_init<<<E_ * H_ / 256, 256, 0, stream>>>(b1, bias1);
  k_tw1<<<dim3(24, 24, E_), dim3(32, 8), 0, stream>>>(w1, lng, lnb, w1T, bias1);
  k_tw2<<<dim3(32, 24, E_), dim3(32, 8), 0, stream>>>(w2, w2T);
  // GEMM1: per expert M=4096, N=768 -> 48 tiles x 16 experts = 768 blocks
  k_gemm256<0><<<E_ * 16 * 3, 512, 0, stream>>>(xn, 0, w1T, H_, bias1, Hact, nullptr);
  // GEMM2 fused with softmax: 16 experts x 64 m-blocks = 1024 blocks
  k_gemm2_sm<<<E_ * 64, 512, 0, stream>>>(Hact, w2T, b2, out1);
  k_market<<<dim3(4, B_), 256, 0, stream>>>(out1, tki, tkv, out0);
}

// Round 4
// 708.926 us; speedup vs baseline: 1.4604x; 1.0882x over previous
//
#include <hip/hip_runtime.h>
#include <hip/hip_bf16.h>
#include <cmath>

#define B_ 4096
#define D_ 768
#define E_ 16
#define H_ 768
#define C_ 1000
#define CP_ 1024
#define K_ 768

typedef __bf16 bf16_t;
typedef __bf16 bf16x8 __attribute__((ext_vector_type(8)));
typedef float f32x4 __attribute__((ext_vector_type(4)));

__device__ __forceinline__ void async_lds16(const void* g, void* l) {
  __builtin_amdgcn_global_load_lds(
      (const __attribute__((address_space(1))) void*)g,
      (__attribute__((address_space(3))) void*)l, 16, 0, 0);
}

// ---------------- router + LayerNorm fused (both read feat once) ----------------
__global__ __launch_bounds__(256) void k_router_ln(
    const float* __restrict__ feat, const float* __restrict__ rw,
    const float* __restrict__ rb, float* __restrict__ gate_out,
    int* __restrict__ tk_idx, float* __restrict__ tk_val,
    bf16_t* __restrict__ xn) {
  int w = threadIdx.x >> 6, lane = threadIdx.x & 63;
  int b = blockIdx.x * 4 + w;
  float acc[E_];
#pragma unroll
  for (int e = 0; e < E_; ++e) acc[e] = 0.f;
  const float* frow = feat + (size_t)b * D_;
  float v[D_ / 64];
  float s = 0.f, sq = 0.f;
#pragma unroll
  for (int it = 0; it < D_ / 64; ++it) {
    int d = it * 64 + lane;
    float f = frow[d];
    v[it] = f; s += f; sq += f * f;
    const float4* r4 = reinterpret_cast<const float4*>(rw + (size_t)d * E_);
    float4 q0 = r4[0], q1 = r4[1], q2 = r4[2], q3 = r4[3];
    acc[0]  += f * q0.x; acc[1]  += f * q0.y; acc[2]  += f * q0.z; acc[3]  += f * q0.w;
    acc[4]  += f * q1.x; acc[5]  += f * q1.y; acc[6]  += f * q1.z; acc[7]  += f * q1.w;
    acc[8]  += f * q2.x; acc[9]  += f * q2.y; acc[10] += f * q2.z; acc[11] += f * q2.w;
    acc[12] += f * q3.x; acc[13] += f * q3.y; acc[14] += f * q3.z; acc[15] += f * q3.w;
  }
#pragma unroll
  for (int off = 32; off; off >>= 1) { s += __shfl_xor(s, off); sq += __shfl_xor(sq, off); }
  float mu = s * (1.f / D_);
  float var = sq * (1.f / D_) - mu * mu;
  float rs = rsqrtf(var + 1e-5f);
  bf16_t* o = xn + (size_t)b * D_;
#pragma unroll
  for (int it = 0; it < D_ / 64; ++it)
    o[it * 64 + lane] = (bf16_t)((v[it] - mu) * rs);
#pragma unroll
  for (int e = 0; e < E_; ++e) {
#pragma unroll
    for (int off = 32; off; off >>= 1) acc[e] += __shfl_xor(acc[e], off);
    acc[e] += rb[e];
  }
  if (lane == 0) {
    float mx = acc[0];
#pragma unroll
    for (int e = 1; e < E_; ++e) mx = fmaxf(mx, acc[e]);
    float p[E_]; float ps = 0.f;
#pragma unroll
    for (int e = 0; e < E_; ++e) { p[e] = expf(acc[e] - mx); ps += p[e]; }
    float inv = 1.f / ps;
    float* go = gate_out + (size_t)b * E_;
#pragma unroll
    for (int e = 0; e < E_; ++e) { p[e] *= inv; go[e] = p[e]; }
    float lg[E_];
#pragma unroll
    for (int e = 0; e < E_; ++e) lg[e] = acc[e];
    int idx4[4]; float v4[4]; float vs = 0.f;
#pragma unroll
    for (int k = 0; k < 4; ++k) {
      int bi = 0; float bv = -1e30f;
#pragma unroll
      for (int e = 0; e < E_; ++e) { if (lg[e] > bv) { bv = lg[e]; bi = e; } }
      idx4[k] = bi; v4[k] = p[bi]; vs += p[bi]; lg[bi] = -1e30f;
    }
    float nv = 1.f / vs;
#pragma unroll
    for (int k = 0; k < 4; ++k) { tk_idx[b * 4 + k] = idx4[k]; tk_val[b * 4 + k] = v4[k] * nv; }
  }
}

// ---- transpose+convert w1 (fold ln_g) + full bias1 = b1 + lnb@w1 (no atomics) ----
// One block per (e, 32-wide h strip); loops all 24 d-strips.
__global__ void k_tw1b(const float* __restrict__ w1, const float* __restrict__ lng,
                       const float* __restrict__ lnb, const float* __restrict__ b1,
                       bf16_t* __restrict__ w1T, float* __restrict__ bias1) {
  __shared__ float t[32][33];
  __shared__ float br[8][33];
  int hT = blockIdx.x * 32, e = blockIdx.y;
  int tx = threadIdx.x, ty = threadIdx.y;
  const float* w1e = w1 + (size_t)e * D_ * H_;
  const float* ge = lng + (size_t)e * D_;
  const float* lb = lnb + (size_t)e * D_;
  bf16_t* o = w1T + (size_t)e * H_ * D_;
  float bsum = 0.f;
  for (int r0 = 0; r0 < D_ / 32; ++r0) {
#pragma unroll
    for (int s = 0; s < 4; ++s) {
      int dl = ty + s * 8;
      int d = r0 * 32 + dl;
      float val = w1e[(size_t)d * H_ + hT + tx];
      t[dl][tx] = val * ge[d];
      bsum += lb[d] * val;
    }
    __syncthreads();
#pragma unroll
    for (int s = 0; s < 4; ++s) {
      int hl = ty + s * 8;
      o[(size_t)(hT + hl) * D_ + r0 * 32 + tx] = (bf16_t)t[tx][hl];
    }
    __syncthreads();
  }
  br[ty][tx] = bsum;
  __syncthreads();
  if (ty == 0) {
    float a = 0.f;
#pragma unroll
    for (int z = 0; z < 8; ++z) a += br[z][tx];
    bias1[(size_t)e * H_ + hT + tx] = b1[(size_t)e * H_ + hT + tx] + a;
  }
}

// ---------------- transpose+convert w2 (pad C->1024 with zeros): w2T[e][c][h] ----------------
__global__ void k_tw2(const float* __restrict__ w2, bf16_t* __restrict__ w2T) {
  __shared__ float t[32][33];
  int e = blockIdx.z, hT = blockIdx.y * 32, cT = blockIdx.x * 32;
  int tx = threadIdx.x, ty = threadIdx.y;
  const float* w2e = w2 + (size_t)e * H_ * C_;
#pragma unroll
  for (int r = 0; r < 4; ++r) {
    int h = hT + ty + r * 8, c = cT + tx;
    t[ty + r * 8][tx] = (c < C_) ? w2e[(size_t)h * C_ + c] : 0.f;
  }
  __syncthreads();
  bf16_t* o = w2T + (size_t)e * CP_ * H_;
#pragma unroll
  for (int r = 0; r < 4; ++r) {
    int c = cT + ty + r * 8;
    o[(size_t)c * H_ + hT + tx] = (bf16_t)t[tx][ty + r * 8];
  }
}

// ---------------- 256x256 8-phase bf16 MFMA GEMM (T2+T3+T4+T5) ----------------
// MODE 0: out = bf16(GELU_exact(C+bias1)) -> Hact[e][m][n], stride H_
// MODE 1: out = bf16(C+b2) -> logits[e][m][n], stride CP_ (all 1024 cols)
// MODE 2: out = fp32(C+b2) -> out1[e][m][n], stride C_, n<1000
template <int MODE>
__global__ __launch_bounds__(512, 2) void k_gemm256(
    const bf16_t* __restrict__ Abase, size_t aStride,
    const bf16_t* __restrict__ Bt, int Np,
    const float* __restrict__ bias,
    bf16_t* __restrict__ outb, float* __restrict__ outf) {
  __shared__ __attribute__((aligned(16))) bf16_t smbuf[2][2][256 * 64];
  int id = blockIdx.x;
  int xcd = id & 7, seq = id >> 3;
  int e, m0, n0;
  if (MODE == 0) {
    int m = seq / 6, rr = seq % 6;
    e = xcd * 2 + rr / 3;
    m0 = m * 256;
    n0 = (rr % 3) * 256;
  } else {
    e = xcd * 2 + (seq >> 6);
    int rr = seq & 63;
    m0 = (rr >> 2) * 256;
    n0 = (rr & 3) * 256;
  }
  const bf16_t* A = Abase + (size_t)e * aStride + (size_t)m0 * K_;
  const bf16_t* Bp = Bt + ((size_t)e * Np + n0) * K_;

  int tid = threadIdx.x;
  int lane = tid & 63;
  int wid = tid >> 6;
  int wm = wid >> 2, wn = wid & 3;
  int fr = lane & 15, hi = lane >> 4;
  int sw0 = (hi ^ (fr & 7)) * 8;

  int srow = tid >> 3;
  int scg = (tid & 7) ^ (srow & 7);
  const bf16_t* asrc = A + (size_t)srow * K_ + scg * 8;
  const bf16_t* bsrc = Bp + (size_t)srow * K_ + scg * 8;

  f32x4 acc[8][4];
#pragma unroll
  for (int i = 0; i < 8; ++i)
#pragma unroll
    for (int j = 0; j < 4; ++j) acc[i][j] = f32x4{0.f, 0.f, 0.f, 0.f};

  auto STAGE = [&](int kt, int nb) {
    bf16_t* ad = &smbuf[nb][0][tid * 8];
    bf16_t* bd = &smbuf[nb][1][tid * 8];
    const bf16_t* as = asrc + kt * 64;
    const bf16_t* bs = bsrc + kt * 64;
#pragma unroll
    for (int s = 0; s < 4; ++s) {
      async_lds16(as + (size_t)s * 64 * K_, ad + s * 4096);
      async_lds16(bs + (size_t)s * 64 * K_, bd + s * 4096);
    }
  };

  bf16x8 af[4][2], bfr[2][2];
  auto COMPUTE = [&](int cur) {
    const bf16_t* Ala = &smbuf[cur][0][(wm * 128 + fr) * 64];
    const bf16_t* Bla = &smbuf[cur][1][(wn * 64 + fr) * 64];
#pragma unroll
    for (int q = 0; q < 4; ++q) {
      const int mq = q >> 1;
      const int nq = (q == 1 || q == 2);
      if (q == 0 || q == 2) {
#pragma unroll
        for (int i = 0; i < 4; ++i)
#pragma unroll
          for (int ks = 0; ks < 2; ++ks)
            af[i][ks] = *(const bf16x8*)&Ala[(mq * 64 + i * 16) * 64 + (sw0 ^ (ks * 32))];
      }
      if (q != 2) {
#pragma unroll
        for (int j = 0; j < 2; ++j)
#pragma unroll
          for (int ks = 0; ks < 2; ++ks)
            bfr[j][ks] = *(const bf16x8*)&Bla[(nq * 32 + j * 16) * 64 + (sw0 ^ (ks * 32))];
      }
      __builtin_amdgcn_s_barrier();
      __builtin_amdgcn_s_setprio(1);
#pragma unroll
      for (int i = 0; i < 4; ++i)
#pragma unroll
        for (int j = 0; j < 2; ++j)
#pragma unroll
          for (int ks = 0; ks < 2; ++ks)
            acc[mq * 4 + i][nq * 2 + j] = __builtin_amdgcn_mfma_f32_16x16x32_bf16(
                af[i][ks], bfr[j][ks], acc[mq * 4 + i][nq * 2 + j], 0, 0, 0);
      __builtin_amdgcn_s_setprio(0);
      __builtin_amdgcn_s_barrier();
    }
  };

  constexpr int NKT = K_ / 64;  // 12
  STAGE(0, 0);
  for (int t = 0; t < NKT - 1; ++t) {
    STAGE(t + 1, (t + 1) & 1);
    asm volatile("s_waitcnt vmcnt(8)" ::: "memory");
    __builtin_amdgcn_s_barrier();
    COMPUTE(t & 1);
  }
  asm volatile("s_waitcnt vmcnt(0)" ::: "memory");
  __builtin_amdgcn_s_barrier();
  COMPUTE((NKT - 1) & 1);

  int rb = hi * 4;
  int cl = fr;
#pragma unroll
  for (int i = 0; i < 8; ++i) {
#pragma unroll
    for (int j = 0; j < 4; ++j) {
      int n = n0 + wn * 64 + j * 16 + cl;
      if (MODE == 0) {
        float bs = bias[(size_t)e * H_ + n];
#pragma unroll
        for (int r = 0; r < 4; ++r) {
          int m = m0 + wm * 128 + i * 16 + rb + r;
          float vv = acc[i][j][r] + bs;
          vv = 0.5f * vv * (1.f + erff(vv * 0.70710678118654752f));
          outb[((size_t)e * B_ + m) * H_ + n] = (bf16_t)vv;
        }
      } else if (MODE == 1) {
        float bs = (n < C_) ? bias[(size_t)e * C_ + n] : 0.f;
#pragma unroll
        for (int r = 0; r < 4; ++r) {
          int m = m0 + wm * 128 + i * 16 + rb + r;
          outb[((size_t)e * B_ + m) * CP_ + n] = (bf16_t)(acc[i][j][r] + bs);
        }
      } else {
        if (n < C_) {
          float bs = bias[(size_t)e * C_ + n];
#pragma unroll
          for (int r = 0; r < 4; ++r) {
            int m = m0 + wm * 128 + i * 16 + rb + r;
            outf[((size_t)e * B_ + m) * C_ + n] = acc[i][j][r] + bs;
          }
        }
      }
    }
  }
}

// ---- fused softmax(all 16 experts of row b) + market mixture ----
// Wave = one batch row b. For each expert: softmax its bf16 logit row (stride CP_)
// -> fp32 probs to out1; accumulate market = sum_e wgt[e]*probs in registers.
__global__ __launch_bounds__(256) void k_sm_market(
    const bf16_t* __restrict__ lg, const int* __restrict__ tki,
    const float* __restrict__ tkv, float* __restrict__ out1,
    float* __restrict__ out0) {
  int w = threadIdx.x >> 6, lane = threadIdx.x & 63;
  int b = blockIdx.x * 4 + w;
  const int* ixp = tki + (size_t)b * 4;
  const float* vvp = tkv + (size_t)b * 4;
  int i0 = ixp[0], i1 = ixp[1], i2 = ixp[2], i3 = ixp[3];
  float v0 = vvp[0], v1 = vvp[1], v2 = vvp[2], v3 = vvp[3];
  float mac[2][8];
#pragma unroll
  for (int it = 0; it < 2; ++it)
#pragma unroll
    for (int q = 0; q < 8; ++q) mac[it][q] = 0.f;
#pragma unroll 2
  for (int e = 0; e < E_; ++e) {
    const bf16_t* row = lg + ((size_t)e * B_ + b) * CP_;
    float f[2][8];
    float mx = -1e30f;
#pragma unroll
    for (int it = 0; it < 2; ++it) {
      int ch = it * 64 + lane;  // 8-elem chunk; valid if < 125 (125*8 = 1000)
      bf16x8 x = *(const bf16x8*)(row + ch * 8);
      if (ch < 125) {
#pragma unroll
        for (int q = 0; q < 8; ++q) { f[it][q] = (float)x[q]; mx = fmaxf(mx, f[it][q]); }
      }
    }
#pragma unroll
    for (int off = 32; off; off >>= 1) mx = fmaxf(mx, __shfl_xor(mx, off));
    float s = 0.f;
#pragma unroll
    for (int it = 0; it < 2; ++it) {
      int ch = it * 64 + lane;
      if (ch < 125) {
#pragma unroll
        for (int q = 0; q < 8; ++q) { f[it][q] = __expf(f[it][q] - mx); s += f[it][q]; }
      }
    }
#pragma unroll
    for (int off = 32; off; off >>= 1) s += __shfl_xor(s, off);
    float inv = 1.f / s;
    float wg = (i0 == e ? v0 : 0.f) + (i1 == e ? v1 : 0.f) +
               (i2 == e ? v2 : 0.f) + (i3 == e ? v3 : 0.f);
    float* orow = out1 + ((size_t)e * B_ + b) * C_;
#pragma unroll
    for (int it = 0; it < 2; ++it) {
      int ch = it * 64 + lane;
      if (ch < 125) {
        float p[8];
#pragma unroll
        for (int q = 0; q < 8; ++q) { p[q] = f[it][q] * inv; mac[it][q] += wg * p[q]; }
        *(float4*)(orow + ch * 8)     = make_float4(p[0], p[1], p[2], p[3]);
        *(float4*)(orow + ch * 8 + 4) = make_float4(p[4], p[5], p[6], p[7]);
      }
    }
  }
  float* mrow = out0 + (size_t)b * C_;
#pragma unroll
  for (int it = 0; it < 2; ++it) {
    int ch = it * 64 + lane;
    if (ch < 125) {
      *(float4*)(mrow + ch * 8)     = make_float4(mac[it][0], mac[it][1], mac[it][2], mac[it][3]);
      *(float4*)(mrow + ch * 8 + 4) = make_float4(mac[it][4], mac[it][5], mac[it][6], mac[it][7]);
    }
  }
}

// ---------------- in-place fp32 row softmax over C=1000 (fallback path) ----------------
__global__ __launch_bounds__(256) void k_softmax(float* __restrict__ p) {
  int w = threadIdx.x >> 6, lane = threadIdx.x & 63;
  size_t r = (size_t)blockIdx.x * 4 + w;
  float* row = p + r * C_;
  float4* row4 = reinterpret_cast<float4*>(row);
  const int n4 = C_ / 4;
  float4 v[4];
  float mx = -1e30f;
#pragma unroll
  for (int i = 0; i < 4; ++i) {
    int idx = i * 64 + lane;
    if (idx < n4) {
      v[i] = row4[idx];
      mx = fmaxf(mx, fmaxf(fmaxf(v[i].x, v[i].y), fmaxf(v[i].z, v[i].w)));
    }
  }
#pragma unroll
  for (int off = 32; off; off >>= 1) mx = fmaxf(mx, __shfl_xor(mx, off));
  float s = 0.f;
#pragma unroll
  for (int i = 0; i < 4; ++i) {
    int idx = i * 64 + lane;
    if (idx < n4) {
      v[i].x = __expf(v[i].x - mx); v[i].y = __expf(v[i].y - mx);
      v[i].z = __expf(v[i].z - mx); v[i].w = __expf(v[i].w - mx);
      s += v[i].x + v[i].y + v[i].z + v[i].w;
    }
  }
#pragma unroll
  for (int off = 32; off; off >>= 1) s += __shfl_xor(s, off);
  float inv = 1.f / s;
#pragma unroll
  for (int i = 0; i < 4; ++i) {
    int idx = i * 64 + lane;
    if (idx < n4) {
      v[i].x *= inv; v[i].y *= inv; v[i].z *= inv; v[i].w *= inv;
      row4[idx] = v[i];
    }
  }
}

// ---------------- market fallback: out0 = sum_k tkv * all_probs[tki] ----------------
__global__ __launch_bounds__(256) void k_market(const float* __restrict__ allp,
                                                const int* __restrict__ tki,
                                                const float* __restrict__ tkv,
                                                float* __restrict__ out0) {
  int b = blockIdx.y;
  int c = blockIdx.x * 256 + threadIdx.x;
  if (c >= C_) return;
  const int* ix = tki + (size_t)b * 4;
  const float* vv = tkv + (size_t)b * 4;
  float s = 0.f;
#pragma unroll
  for (int k = 0; k < 4; ++k)
    s += vv[k] * allp[((size_t)ix[k] * B_ + b) * C_ + c];
  out0[(size_t)b * C_ + c] = s;
}

extern "C" void kernel_launch(void* const* d_in, const int* in_sizes, int n_in,
                              void* d_out, int out_size, void* d_ws, size_t ws_size,
                              hipStream_t stream) {
  const float* feat = (const float*)d_in[0];
  const float* rw   = (const float*)d_in[1];
  const float* rb   = (const float*)d_in[2];
  const float* lng  = (const float*)d_in[3];
  const float* lnb  = (const float*)d_in[4];
  const float* w1   = (const float*)d_in[5];
  const float* b1   = (const float*)d_in[6];
  const float* w2   = (const float*)d_in[7];
  const float* b2   = (const float*)d_in[8];

  float* out0 = (float*)d_out;                   // market_probs [4096,1000]
  float* out1 = out0 + (size_t)B_ * C_;          // all_probs [16,4096,1000]
  float* out2 = out1 + (size_t)E_ * B_ * C_;     // gate_probs [4096,16]

  char* ws = (char*)d_ws;
  size_t off = 0;
  auto take = [&](size_t bytes) -> void* {
    void* p = ws + off;
    off += (bytes + 255) & ~(size_t)255;
    return p;
  };
  bf16_t* xn   = (bf16_t*)take((size_t)B_ * D_ * 2);
  bf16_t* w1T  = (bf16_t*)take((size_t)E_ * H_ * D_ * 2);
  bf16_t* w2T  = (bf16_t*)take((size_t)E_ * CP_ * H_ * 2);
  float* bias1 = (float*)take((size_t)E_ * H_ * 4);
  int* tki     = (int*)take((size_t)B_ * 4 * 4);
  float* tkv   = (float*)take((size_t)B_ * 4 * 4);
  bf16_t* Hact = (bf16_t*)take((size_t)E_ * B_ * H_ * 2);
  size_t logit_bytes = (size_t)E_ * B_ * CP_ * 2;
  bool use_b16_logits = (off + logit_bytes) <= ws_size;   // constant across calls: graph-safe
  bf16_t* logitsB = use_b16_logits ? (bf16_t*)take(logit_bytes) : nullptr;

  k_router_ln<<<B_ / 4, 256, 0, stream>>>(feat, rw, rb, out2, tki, tkv, xn);
  k_tw1b<<<dim3(24, E_), dim3(32, 8), 0, stream>>>(w1, lng, lnb, b1, w1T, bias1);
  k_tw2<<<dim3(32, 24, E_), dim3(32, 8), 0, stream>>>(w2, w2T);
  // GEMM1: per expert M=4096, N=768 -> 48 tiles x 16 experts = 768 blocks
  k_gemm256<0><<<E_ * 16 * 3, 512, 0, stream>>>(xn, 0, w1T, H_, bias1, Hact, nullptr);
  if (use_b16_logits) {
    // GEMM2: per expert M=4096, N=1024 -> 64 tiles x 16 experts = 1024 blocks
    k_gemm256<1><<<E_ * 16 * 4, 512, 0, stream>>>(Hact, (size_t)B_ * H_, w2T, CP_, b2, logitsB, nullptr);
    // fused softmax (16 experts/row) + market mixture
    k_sm_market<<<B_ / 4, 256, 0, stream>>>(logitsB, tki, tkv, out1, out0);
  } else {
    k_gemm256<2><<<E_ * 16 * 4, 512, 0, stream>>>(Hact, (size_t)B_ * H_, w2T, CP_, b2, nullptr, out1);
    k_softmax<<<(E_ * B_) / 4, 256, 0, stream>>>(out1);
    k_market<<<dim3(4, B_), 256, 0, stream>>>(out1, tki, tkv, out0);
  }
}

// Round 5
// 665.027 us; speedup vs baseline: 1.5568x; 1.0660x over previous
//
#include <hip/hip_runtime.h>
#include <hip/hip_bf16.h>
#include <cmath>

#define B_ 4096
#define D_ 768
#define E_ 16
#define H_ 768
#define C_ 1000
#define CP_ 1024
#define K_ 768

typedef __bf16 bf16_t;
typedef __bf16 bf16x8 __attribute__((ext_vector_type(8)));
typedef float f32x4 __attribute__((ext_vector_type(4)));

__device__ __forceinline__ void async_lds16(const void* g, void* l) {
  __builtin_amdgcn_global_load_lds(
      (const __attribute__((address_space(1))) void*)g,
      (__attribute__((address_space(3))) void*)l, 16, 0, 0);
}

// Fast exact-GELU: x * Phi(x), Phi via A&S 26.2.17 (|eps| < 7.5e-8, far below
// bf16 output rounding). ~13 instrs vs ~35-40 for OCML erff.
__device__ __forceinline__ float gelu_f(float x) {
  float ax = fabsf(x);
  float t = __builtin_amdgcn_rcpf(fmaf(0.2316419f, ax, 1.0f));
  float p = t * fmaf(t, fmaf(t, fmaf(t, fmaf(t, 1.330274429f, -1.821255978f),
                                     1.781477937f), -0.356563782f), 0.319381530f);
  float phi = 0.3989422804f * __expf(-0.5f * ax * ax);
  float q = phi * p;                      // = 1 - Phi(ax)
  float cdf = (x >= 0.f) ? (1.f - q) : q; // Phi(x) by symmetry
  return x * cdf;
}

// ---------------- router + LayerNorm fused (both read feat once) ----------------
__global__ __launch_bounds__(256) void k_router_ln(
    const float* __restrict__ feat, const float* __restrict__ rw,
    const float* __restrict__ rb, float* __restrict__ gate_out,
    int* __restrict__ tk_idx, float* __restrict__ tk_val,
    bf16_t* __restrict__ xn) {
  int w = threadIdx.x >> 6, lane = threadIdx.x & 63;
  int b = blockIdx.x * 4 + w;
  float acc[E_];
#pragma unroll
  for (int e = 0; e < E_; ++e) acc[e] = 0.f;
  const float* frow = feat + (size_t)b * D_;
  float v[D_ / 64];
  float s = 0.f, sq = 0.f;
#pragma unroll
  for (int it = 0; it < D_ / 64; ++it) {
    int d = it * 64 + lane;
    float f = frow[d];
    v[it] = f; s += f; sq += f * f;
    const float4* r4 = reinterpret_cast<const float4*>(rw + (size_t)d * E_);
    float4 q0 = r4[0], q1 = r4[1], q2 = r4[2], q3 = r4[3];
    acc[0]  += f * q0.x; acc[1]  += f * q0.y; acc[2]  += f * q0.z; acc[3]  += f * q0.w;
    acc[4]  += f * q1.x; acc[5]  += f * q1.y; acc[6]  += f * q1.z; acc[7]  += f * q1.w;
    acc[8]  += f * q2.x; acc[9]  += f * q2.y; acc[10] += f * q2.z; acc[11] += f * q2.w;
    acc[12] += f * q3.x; acc[13] += f * q3.y; acc[14] += f * q3.z; acc[15] += f * q3.w;
  }
#pragma unroll
  for (int off = 32; off; off >>= 1) { s += __shfl_xor(s, off); sq += __shfl_xor(sq, off); }
  float mu = s * (1.f / D_);
  float var = sq * (1.f / D_) - mu * mu;
  float rs = rsqrtf(var + 1e-5f);
  bf16_t* o = xn + (size_t)b * D_;
#pragma unroll
  for (int it = 0; it < D_ / 64; ++it)
    o[it * 64 + lane] = (bf16_t)((v[it] - mu) * rs);
#pragma unroll
  for (int e = 0; e < E_; ++e) {
#pragma unroll
    for (int off = 32; off; off >>= 1) acc[e] += __shfl_xor(acc[e], off);
    acc[e] += rb[e];
  }
  if (lane == 0) {
    float mx = acc[0];
#pragma unroll
    for (int e = 1; e < E_; ++e) mx = fmaxf(mx, acc[e]);
    float p[E_]; float ps = 0.f;
#pragma unroll
    for (int e = 0; e < E_; ++e) { p[e] = expf(acc[e] - mx); ps += p[e]; }
    float inv = 1.f / ps;
    float* go = gate_out + (size_t)b * E_;
#pragma unroll
    for (int e = 0; e < E_; ++e) { p[e] *= inv; go[e] = p[e]; }
    float lg[E_];
#pragma unroll
    for (int e = 0; e < E_; ++e) lg[e] = acc[e];
    int idx4[4]; float v4[4]; float vs = 0.f;
#pragma unroll
    for (int k = 0; k < 4; ++k) {
      int bi = 0; float bv = -1e30f;
#pragma unroll
      for (int e = 0; e < E_; ++e) { if (lg[e] > bv) { bv = lg[e]; bi = e; } }
      idx4[k] = bi; v4[k] = p[bi]; vs += p[bi]; lg[bi] = -1e30f;
    }
    float nv = 1.f / vs;
#pragma unroll
    for (int k = 0; k < 4; ++k) { tk_idx[b * 4 + k] = idx4[k]; tk_val[b * 4 + k] = v4[k] * nv; }
  }
}

// ---------------- bias1 init: bias1 = b1 ----------------
__global__ __launch_bounds__(256) void k_bias_init(const float* __restrict__ b1,
                                                   float* __restrict__ bias1) {
  int i = blockIdx.x * 256 + threadIdx.x;
  bias1[i] = b1[i];
}

// ---- transpose+convert w1 (fold ln_g) + accumulate bias contrib lnb@w1 ----
__global__ void k_tw1(const float* __restrict__ w1, const float* __restrict__ lng,
                      const float* __restrict__ lnb, bf16_t* __restrict__ w1T,
                      float* __restrict__ bias1) {
  __shared__ float t[32][33];
  __shared__ float br[8][33];
  int e = blockIdx.z, dT = blockIdx.y * 32, hT = blockIdx.x * 32;
  int tx = threadIdx.x, ty = threadIdx.y;
  const float* w1e = w1 + (size_t)e * D_ * H_;
  const float* ge = lng + (size_t)e * D_;
  const float* lb = lnb + (size_t)e * D_;
  float bsum = 0.f;
#pragma unroll
  for (int r = 0; r < 4; ++r) {
    int d = dT + ty + r * 8;
    float val = w1e[(size_t)d * H_ + hT + tx];
    t[ty + r * 8][tx] = val * ge[d];
    bsum += lb[d] * val;
  }
  br[ty][tx] = bsum;
  __syncthreads();
  bf16_t* o = w1T + (size_t)e * H_ * D_;
#pragma unroll
  for (int r = 0; r < 4; ++r) {
    int h = hT + ty + r * 8;
    o[(size_t)h * D_ + dT + tx] = (bf16_t)t[tx][ty + r * 8];
  }
  if (ty == 0) {
    float a = 0.f;
#pragma unroll
    for (int z = 0; z < 8; ++z) a += br[z][tx];
    atomicAdd(&bias1[(size_t)e * H_ + hT + tx], a);
  }
}

// ---------------- transpose+convert w2 (pad C->1024 with zeros): w2T[e][c][h] ----------------
__global__ void k_tw2(const float* __restrict__ w2, bf16_t* __restrict__ w2T) {
  __shared__ float t[32][33];
  int e = blockIdx.z, hT = blockIdx.y * 32, cT = blockIdx.x * 32;
  int tx = threadIdx.x, ty = threadIdx.y;
  const float* w2e = w2 + (size_t)e * H_ * C_;
#pragma unroll
  for (int r = 0; r < 4; ++r) {
    int h = hT + ty + r * 8, c = cT + tx;
    t[ty + r * 8][tx] = (c < C_) ? w2e[(size_t)h * C_ + c] : 0.f;
  }
  __syncthreads();
  bf16_t* o = w2T + (size_t)e * CP_ * H_;
#pragma unroll
  for (int r = 0; r < 4; ++r) {
    int c = cT + ty + r * 8;
    o[(size_t)c * H_ + hT + tx] = (bf16_t)t[tx][ty + r * 8];
  }
}

// ---------------- 256x256 8-phase bf16 MFMA GEMM (T2+T3+T4+T5) ----------------
// MODE 0: out = bf16(GELU_exact(C+bias1)) -> Hact[e][m][n], stride H_
// MODE 1: out = bf16(C+b2) -> logits[e][m][n], stride CP_ (all 1024 cols)
// MODE 2: out = fp32(C+b2) -> out1[e][m][n], stride C_, n<1000
template <int MODE>
__global__ __launch_bounds__(512, 2) void k_gemm256(
    const bf16_t* __restrict__ Abase, size_t aStride,
    const bf16_t* __restrict__ Bt, int Np,
    const float* __restrict__ bias,
    bf16_t* __restrict__ outb, float* __restrict__ outf) {
  __shared__ __attribute__((aligned(16))) bf16_t smbuf[2][2][256 * 64];
  int id = blockIdx.x;
  int xcd = id & 7, seq = id >> 3;
  int e, m0, n0;
  if (MODE == 0) {
    int m = seq / 6, rr = seq % 6;
    e = xcd * 2 + rr / 3;
    m0 = m * 256;
    n0 = (rr % 3) * 256;
  } else {
    e = xcd * 2 + (seq >> 6);
    int rr = seq & 63;
    m0 = (rr >> 2) * 256;
    n0 = (rr & 3) * 256;
  }
  const bf16_t* A = Abase + (size_t)e * aStride + (size_t)m0 * K_;
  const bf16_t* Bp = Bt + ((size_t)e * Np + n0) * K_;

  int tid = threadIdx.x;
  int lane = tid & 63;
  int wid = tid >> 6;
  int wm = wid >> 2, wn = wid & 3;
  int fr = lane & 15, hi = lane >> 4;
  int sw0 = (hi ^ (fr & 7)) * 8;

  int srow = tid >> 3;
  int scg = (tid & 7) ^ (srow & 7);
  const bf16_t* asrc = A + (size_t)srow * K_ + scg * 8;
  const bf16_t* bsrc = Bp + (size_t)srow * K_ + scg * 8;

  f32x4 acc[8][4];
#pragma unroll
  for (int i = 0; i < 8; ++i)
#pragma unroll
    for (int j = 0; j < 4; ++j) acc[i][j] = f32x4{0.f, 0.f, 0.f, 0.f};

  auto STAGE = [&](int kt, int nb) {
    bf16_t* ad = &smbuf[nb][0][tid * 8];
    bf16_t* bd = &smbuf[nb][1][tid * 8];
    const bf16_t* as = asrc + kt * 64;
    const bf16_t* bs = bsrc + kt * 64;
#pragma unroll
    for (int s = 0; s < 4; ++s) {
      async_lds16(as + (size_t)s * 64 * K_, ad + s * 4096);
      async_lds16(bs + (size_t)s * 64 * K_, bd + s * 4096);
    }
  };

  bf16x8 af[4][2], bfr[2][2];
  auto COMPUTE = [&](int cur) {
    const bf16_t* Ala = &smbuf[cur][0][(wm * 128 + fr) * 64];
    const bf16_t* Bla = &smbuf[cur][1][(wn * 64 + fr) * 64];
#pragma unroll
    for (int q = 0; q < 4; ++q) {
      const int mq = q >> 1;
      const int nq = (q == 1 || q == 2);
      if (q == 0 || q == 2) {
#pragma unroll
        for (int i = 0; i < 4; ++i)
#pragma unroll
          for (int ks = 0; ks < 2; ++ks)
            af[i][ks] = *(const bf16x8*)&Ala[(mq * 64 + i * 16) * 64 + (sw0 ^ (ks * 32))];
      }
      if (q != 2) {
#pragma unroll
        for (int j = 0; j < 2; ++j)
#pragma unroll
          for (int ks = 0; ks < 2; ++ks)
            bfr[j][ks] = *(const bf16x8*)&Bla[(nq * 32 + j * 16) * 64 + (sw0 ^ (ks * 32))];
      }
      __builtin_amdgcn_s_barrier();
      __builtin_amdgcn_s_setprio(1);
#pragma unroll
      for (int i = 0; i < 4; ++i)
#pragma unroll
        for (int j = 0; j < 2; ++j)
#pragma unroll
          for (int ks = 0; ks < 2; ++ks)
            acc[mq * 4 + i][nq * 2 + j] = __builtin_amdgcn_mfma_f32_16x16x32_bf16(
                af[i][ks], bfr[j][ks], acc[mq * 4 + i][nq * 2 + j], 0, 0, 0);
      __builtin_amdgcn_s_setprio(0);
      __builtin_amdgcn_s_barrier();
    }
  };

  constexpr int NKT = K_ / 64;  // 12
  STAGE(0, 0);
  for (int t = 0; t < NKT - 1; ++t) {
    STAGE(t + 1, (t + 1) & 1);
    asm volatile("s_waitcnt vmcnt(8)" ::: "memory");
    __builtin_amdgcn_s_barrier();
    COMPUTE(t & 1);
  }
  asm volatile("s_waitcnt vmcnt(0)" ::: "memory");
  __builtin_amdgcn_s_barrier();
  COMPUTE((NKT - 1) & 1);

  int rb = hi * 4;
  int cl = fr;
#pragma unroll
  for (int i = 0; i < 8; ++i) {
#pragma unroll
    for (int j = 0; j < 4; ++j) {
      int n = n0 + wn * 64 + j * 16 + cl;
      if (MODE == 0) {
        float bs = bias[(size_t)e * H_ + n];
#pragma unroll
        for (int r = 0; r < 4; ++r) {
          int m = m0 + wm * 128 + i * 16 + rb + r;
          float vv = acc[i][j][r] + bs;
          outb[((size_t)e * B_ + m) * H_ + n] = (bf16_t)gelu_f(vv);
        }
      } else if (MODE == 1) {
        float bs = (n < C_) ? bias[(size_t)e * C_ + n] : 0.f;
#pragma unroll
        for (int r = 0; r < 4; ++r) {
          int m = m0 + wm * 128 + i * 16 + rb + r;
          outb[((size_t)e * B_ + m) * CP_ + n] = (bf16_t)(acc[i][j][r] + bs);
        }
      } else {
        if (n < C_) {
          float bs = bias[(size_t)e * C_ + n];
#pragma unroll
          for (int r = 0; r < 4; ++r) {
            int m = m0 + wm * 128 + i * 16 + rb + r;
            outf[((size_t)e * B_ + m) * C_ + n] = acc[i][j][r] + bs;
          }
        }
      }
    }
  }
}

// ---- fused softmax(all 16 experts of row b) + market mixture ----
__global__ __launch_bounds__(256) void k_sm_market(
    const bf16_t* __restrict__ lg, const int* __restrict__ tki,
    const float* __restrict__ tkv, float* __restrict__ out1,
    float* __restrict__ out0) {
  int w = threadIdx.x >> 6, lane = threadIdx.x & 63;
  int b = blockIdx.x * 4 + w;
  const int* ixp = tki + (size_t)b * 4;
  const float* vvp = tkv + (size_t)b * 4;
  int i0 = ixp[0], i1 = ixp[1], i2 = ixp[2], i3 = ixp[3];
  float v0 = vvp[0], v1 = vvp[1], v2 = vvp[2], v3 = vvp[3];
  float mac[2][8];
#pragma unroll
  for (int it = 0; it < 2; ++it)
#pragma unroll
    for (int q = 0; q < 8; ++q) mac[it][q] = 0.f;
#pragma unroll 2
  for (int e = 0; e < E_; ++e) {
    const bf16_t* row = lg + ((size_t)e * B_ + b) * CP_;
    float f[2][8];
    float mx = -1e30f;
#pragma unroll
    for (int it = 0; it < 2; ++it) {
      int ch = it * 64 + lane;  // 8-elem chunk; valid if < 125 (125*8 = 1000)
      bf16x8 x = *(const bf16x8*)(row + ch * 8);
      if (ch < 125) {
#pragma unroll
        for (int q = 0; q < 8; ++q) { f[it][q] = (float)x[q]; mx = fmaxf(mx, f[it][q]); }
      }
    }
#pragma unroll
    for (int off = 32; off; off >>= 1) mx = fmaxf(mx, __shfl_xor(mx, off));
    float s = 0.f;
#pragma unroll
    for (int it = 0; it < 2; ++it) {
      int ch = it * 64 + lane;
      if (ch < 125) {
#pragma unroll
        for (int q = 0; q < 8; ++q) { f[it][q] = __expf(f[it][q] - mx); s += f[it][q]; }
      }
    }
#pragma unroll
    for (int off = 32; off; off >>= 1) s += __shfl_xor(s, off);
    float inv = 1.f / s;
    float wg = (i0 == e ? v0 : 0.f) + (i1 == e ? v1 : 0.f) +
               (i2 == e ? v2 : 0.f) + (i3 == e ? v3 : 0.f);
    float* orow = out1 + ((size_t)e * B_ + b) * C_;
#pragma unroll
    for (int it = 0; it < 2; ++it) {
      int ch = it * 64 + lane;
      if (ch < 125) {
        float p[8];
#pragma unroll
        for (int q = 0; q < 8; ++q) { p[q] = f[it][q] * inv; mac[it][q] += wg * p[q]; }
        *(float4*)(orow + ch * 8)     = make_float4(p[0], p[1], p[2], p[3]);
        *(float4*)(orow + ch * 8 + 4) = make_float4(p[4], p[5], p[6], p[7]);
      }
    }
  }
  float* mrow = out0 + (size_t)b * C_;
#pragma unroll
  for (int it = 0; it < 2; ++it) {
    int ch = it * 64 + lane;
    if (ch < 125) {
      *(float4*)(mrow + ch * 8)     = make_float4(mac[it][0], mac[it][1], mac[it][2], mac[it][3]);
      *(float4*)(mrow + ch * 8 + 4) = make_float4(mac[it][4], mac[it][5], mac[it][6], mac[it][7]);
    }
  }
}

// ---------------- in-place fp32 row softmax over C=1000 (fallback path) ----------------
__global__ __launch_bounds__(256) void k_softmax(float* __restrict__ p) {
  int w = threadIdx.x >> 6, lane = threadIdx.x & 63;
  size_t r = (size_t)blockIdx.x * 4 + w;
  float* row = p + r * C_;
  float4* row4 = reinterpret_cast<float4*>(row);
  const int n4 = C_ / 4;
  float4 v[4];
  float mx = -1e30f;
#pragma unroll
  for (int i = 0; i < 4; ++i) {
    int idx = i * 64 + lane;
    if (idx < n4) {
      v[i] = row4[idx];
      mx = fmaxf(mx, fmaxf(fmaxf(v[i].x, v[i].y), fmaxf(v[i].z, v[i].w)));
    }
  }
#pragma unroll
  for (int off = 32; off; off >>= 1) mx = fmaxf(mx, __shfl_xor(mx, off));
  float s = 0.f;
#pragma unroll
  for (int i = 0; i < 4; ++i) {
    int idx = i * 64 + lane;
    if (idx < n4) {
      v[i].x = __expf(v[i].x - mx); v[i].y = __expf(v[i].y - mx);
      v[i].z = __expf(v[i].z - mx); v[i].w = __expf(v[i].w - mx);
      s += v[i].x + v[i].y + v[i].z + v[i].w;
    }
  }
#pragma unroll
  for (int off = 32; off; off >>= 1) s += __shfl_xor(s, off);
  float inv = 1.f / s;
#pragma unroll
  for (int i = 0; i < 4; ++i) {
    int idx = i * 64 + lane;
    if (idx < n4) {
      v[i].x *= inv; v[i].y *= inv; v[i].z *= inv; v[i].w *= inv;
      row4[idx] = v[i];
    }
  }
}

// ---------------- market fallback: out0 = sum_k tkv * all_probs[tki] ----------------
__global__ __launch_bounds__(256) void k_market(const float* __restrict__ allp,
                                                const int* __restrict__ tki,
                                                const float* __restrict__ tkv,
                                                float* __restrict__ out0) {
  int b = blockIdx.y;
  int c = blockIdx.x * 256 + threadIdx.x;
  if (c >= C_) return;
  const int* ix = tki + (size_t)b * 4;
  const float* vv = tkv + (size_t)b * 4;
  float s = 0.f;
#pragma unroll
  for (int k = 0; k < 4; ++k)
    s += vv[k] * allp[((size_t)ix[k] * B_ + b) * C_ + c];
  out0[(size_t)b * C_ + c] = s;
}

extern "C" void kernel_launch(void* const* d_in, const int* in_sizes, int n_in,
                              void* d_out, int out_size, void* d_ws, size_t ws_size,
                              hipStream_t stream) {
  const float* feat = (const float*)d_in[0];
  const float* rw   = (const float*)d_in[1];
  const float* rb   = (const float*)d_in[2];
  const float* lng  = (const float*)d_in[3];
  const float* lnb  = (const float*)d_in[4];
  const float* w1   = (const float*)d_in[5];
  const float* b1   = (const float*)d_in[6];
  const float* w2   = (const float*)d_in[7];
  const float* b2   = (const float*)d_in[8];

  float* out0 = (float*)d_out;                   // market_probs [4096,1000]
  float* out1 = out0 + (size_t)B_ * C_;          // all_probs [16,4096,1000]
  float* out2 = out1 + (size_t)E_ * B_ * C_;     // gate_probs [4096,16]

  char* ws = (char*)d_ws;
  size_t off = 0;
  auto take = [&](size_t bytes) -> void* {
    void* p = ws + off;
    off += (bytes + 255) & ~(size_t)255;
    return p;
  };
  bf16_t* xn   = (bf16_t*)take((size_t)B_ * D_ * 2);
  bf16_t* w1T  = (bf16_t*)take((size_t)E_ * H_ * D_ * 2);
  bf16_t* w2T  = (bf16_t*)take((size_t)E_ * CP_ * H_ * 2);
  float* bias1 = (float*)take((size_t)E_ * H_ * 4);
  int* tki     = (int*)take((size_t)B_ * 4 * 4);
  float* tkv   = (float*)take((size_t)B_ * 4 * 4);
  bf16_t* Hact = (bf16_t*)take((size_t)E_ * B_ * H_ * 2);
  size_t logit_bytes = (size_t)E_ * B_ * CP_ * 2;
  bool use_b16_logits = (off + logit_bytes) <= ws_size;   // constant across calls: graph-safe
  bf16_t* logitsB = use_b16_logits ? (bf16_t*)take(logit_bytes) : nullptr;

  k_router_ln<<<B_ / 4, 256, 0, stream>>>(feat, rw, rb, out2, tki, tkv, xn);
  k_bias_init<<<E_ * H_ / 256, 256, 0, stream>>>(b1, bias1);
  k_tw1<<<dim3(24, 24, E_), dim3(32, 8), 0, stream>>>(w1, lng, lnb, w1T, bias1);
  k_tw2<<<dim3(32, 24, E_), dim3(32, 8), 0, stream>>>(w2, w2T);
  // GEMM1: per expert M=4096, N=768 -> 48 tiles x 16 experts = 768 blocks
  k_gemm256<0><<<E_ * 16 * 3, 512, 0, stream>>>(xn, 0, w1T, H_, bias1, Hact, nullptr);
  if (use_b16_logits) {
    // GEMM2: per expert M=4096, N=1024 -> 64 tiles x 16 experts = 1024 blocks
    k_gemm256<1><<<E_ * 16 * 4, 512, 0, stream>>>(Hact, (size_t)B_ * H_, w2T, CP_, b2, logitsB, nullptr);
    // fused softmax (16 experts/row) + market mixture
    k_sm_market<<<B_ / 4, 256, 0, stream>>>(logitsB, tki, tkv, out1, out0);
  } else {
    k_gemm256<2><<<E_ * 16 * 4, 512, 0, stream>>>(Hact, (size_t)B_ * H_, w2T, CP_, b2, nullptr, out1);
    k_softmax<<<(E_ * B_) / 4, 256, 0, stream>>>(out1);
    k_market<<<dim3(4, B_), 256, 0, stream>>>(out1, tki, tkv, out0);
  }
}